// Round 1
// baseline (1328.366 us; speedup 1.0000x reference)
//
#include <hip/hip_runtime.h>
#include <math.h>

namespace {

constexpr int B = 16, N = 1024, E = 32768, HEADS = 4, OC = 8;
constexpr int D_IN = 33, A_DIM = 8, DM = 16, DO = 32;
constexpr int F = D_IN + A_DIM + 1;  // 42

__device__ __forceinline__ void atomicMaxF(float* addr, float v) {
  // ordered-int trick; addr must be initialized to -inf
  if (v >= 0.f) atomicMax((int*)addr, __float_as_int(v));
  else          atomicMin((unsigned int*)addr, __float_as_uint(v));
}

// ---- init: out <- gat_b broadcast, m <- -inf, den/rowsum <- 0 ----
__global__ void k_init(float* __restrict__ out, const float* __restrict__ gat_b,
                       float* __restrict__ m, float* __restrict__ den,
                       float* __restrict__ rs) {
  int i = blockIdx.x * blockDim.x + threadIdx.x;
  if (i < B * N * DO) out[i] = gat_b[i & (DO - 1)];
  if (i < B * N * HEADS) { m[i] = -INFINITY; den[i] = 0.f; rs[i] = 0.f; }
}

// ---- per-node chain: fc_* -> fuse attn -> proj -> post -> LN -> gat_w -> a_s/a_d ----
__global__ __launch_bounds__(64) void k_node(
    const float* __restrict__ H,
    const float* __restrict__ fc_s_w, const float* __restrict__ fc_s_b,
    const float* __restrict__ fc_a_w, const float* __restrict__ fc_a_b,
    const float* __restrict__ fc_r_w, const float* __restrict__ fc_r_b,
    const float* __restrict__ fuse_q, const float* __restrict__ fuse_k_w,
    const float* __restrict__ fuse_v_w, const float* __restrict__ proj_w,
    const float* __restrict__ proj_b, const float* __restrict__ post_w,
    const float* __restrict__ post_b, const float* __restrict__ ln_g,
    const float* __restrict__ ln_b, const float* __restrict__ gat_w,
    const float* __restrict__ att_src, const float* __restrict__ att_dst,
    float* __restrict__ x_out, float* __restrict__ as_out, float* __restrict__ ad_out) {
  int node = blockIdx.x * blockDim.x + threadIdx.x;
  if (node >= B * N) return;

  const float* hin = H + (size_t)node * F;
  float hv[F];
#pragma unroll
  for (int i = 0; i < F; i++) hv[i] = hin[i];

  // tok = [s@Ws^T+bs, a@Wa^T+ba, r@Wr^T+br]  (3,16)
  float tok[3][DM];
#pragma unroll
  for (int j = 0; j < DM; j++) {
    float acc = fc_s_b[j];
#pragma unroll
    for (int i = 0; i < D_IN; i++) acc = fmaf(hv[i], fc_s_w[j * D_IN + i], acc);
    tok[0][j] = acc;
    float acc2 = fc_a_b[j];
#pragma unroll
    for (int i = 0; i < A_DIM; i++) acc2 = fmaf(hv[D_IN + i], fc_a_w[j * A_DIM + i], acc2);
    tok[1][j] = acc2;
    tok[2][j] = fmaf(hv[F - 1], fc_r_w[j], fc_r_b[j]);
  }

  // K = tok @ fuse_k_w^T ; V = tok @ fuse_v_w^T
  float Kf[3][DM], Vf[3][DM];
#pragma unroll
  for (int t = 0; t < 3; t++) {
#pragma unroll
    for (int j = 0; j < DM; j++) {
      float ak = 0.f, av = 0.f;
#pragma unroll
      for (int d = 0; d < DM; d++) {
        ak = fmaf(tok[t][d], fuse_k_w[j * DM + d], ak);
        av = fmaf(tok[t][d], fuse_v_w[j * DM + d], av);
      }
      Kf[t][j] = ak; Vf[t][j] = av;
    }
  }

  // attn[q][t] = fuse_q[q].K[t] / 4 ; softmax over t; wbar[t] = mean_q w[q][t]
  float wbar[3] = {0.f, 0.f, 0.f};
#pragma unroll
  for (int q = 0; q < 3; q++) {
    float att[3];
#pragma unroll
    for (int t = 0; t < 3; t++) {
      float acc = 0.f;
#pragma unroll
      for (int d = 0; d < DM; d++) acc = fmaf(fuse_q[q * DM + d], Kf[t][d], acc);
      att[t] = acc * 0.25f;
    }
    float mx = fmaxf(att[0], fmaxf(att[1], att[2]));
    float e0 = expf(att[0] - mx), e1 = expf(att[1] - mx), e2 = expf(att[2] - mx);
    float inv = 1.f / (e0 + e1 + e2);
    wbar[0] += e0 * inv; wbar[1] += e1 * inv; wbar[2] += e2 * inv;
  }

  // fused = relu(mean_q w@V)
  float fused[DM];
#pragma unroll
  for (int d = 0; d < DM; d++) {
    float f = (wbar[0] * Vf[0][d] + wbar[1] * Vf[1][d] + wbar[2] * Vf[2][d]) * (1.f / 3.f);
    fused[d] = fmaxf(f, 0.f);
  }

  // z = fused @ proj^T + b
  float z[DO];
#pragma unroll
  for (int o = 0; o < DO; o++) {
    float acc = proj_b[o];
#pragma unroll
    for (int d = 0; d < DM; d++) acc = fmaf(fused[d], proj_w[o * DM + d], acc);
    z[o] = acc;
  }

  // h = relu(z @ post^T + b); LayerNorm
  float h2[DO]; float mu = 0.f;
#pragma unroll
  for (int o = 0; o < DO; o++) {
    float acc = post_b[o];
#pragma unroll
    for (int d = 0; d < DO; d++) acc = fmaf(z[d], post_w[o * DO + d], acc);
    acc = fmaxf(acc, 0.f);
    h2[o] = acc; mu += acc;
  }
  mu *= (1.f / DO);
  float var = 0.f;
#pragma unroll
  for (int o = 0; o < DO; o++) { float dd = h2[o] - mu; var = fmaf(dd, dd, var); }
  var *= (1.f / DO);
  float rstd = rsqrtf(var + 1e-5f);
  float Hn[DO];
#pragma unroll
  for (int o = 0; o < DO; o++) Hn[o] = fmaf((h2[o] - mu) * rstd, ln_g[o], ln_b[o]);

  // x = Hn @ gat_w^T ; a_s, a_d
  float* xrow = x_out + (size_t)node * (HEADS * OC);
#pragma unroll
  for (int hh = 0; hh < HEADS; hh++) {
    float as = 0.f, ad = 0.f;
#pragma unroll
    for (int oc = 0; oc < OC; oc++) {
      int k = hh * OC + oc;
      float acc = 0.f;
#pragma unroll
      for (int d = 0; d < DO; d++) acc = fmaf(Hn[d], gat_w[k * DO + d], acc);
      xrow[k] = acc;
      as = fmaf(acc, att_src[k], as);
      ad = fmaf(acc, att_dst[k], ad);
    }
    as_out[node * HEADS + hh] = as;
    ad_out[node * HEADS + hh] = ad;
  }
}

// ---- pass 1: e = leakyrelu(a_s[src]+a_d[dst]); segment max by dst ----
__global__ void k_edge_max(const int* __restrict__ ei,
                           const float* __restrict__ as_, const float* __restrict__ ad_,
                           float* __restrict__ e_out, float* __restrict__ m_) {
  int idx = blockIdx.x * blockDim.x + threadIdx.x;
  if (idx >= B * E) return;
  int eidx = idx & (E - 1), b = idx >> 15;
  int s = ei[eidx], d = ei[E + eidx];
#pragma unroll
  for (int h = 0; h < HEADS; h++) {
    float v = as_[(b * N + s) * HEADS + h] + ad_[(b * N + d) * HEADS + h];
    v = v >= 0.f ? v : 0.2f * v;
    e_out[(size_t)idx * HEADS + h] = v;
    atomicMaxF(&m_[(b * N + d) * HEADS + h], v);
  }
}

// ---- pass 2: ex = exp(e - m[dst]); den += ex ----
__global__ void k_edge_exp(const int* __restrict__ ei, const float* __restrict__ m_,
                           float* __restrict__ e_io, float* __restrict__ den_) {
  int idx = blockIdx.x * blockDim.x + threadIdx.x;
  if (idx >= B * E) return;
  int eidx = idx & (E - 1), b = idx >> 15;
  int d = ei[E + eidx];
#pragma unroll
  for (int h = 0; h < HEADS; h++) {
    float ex = expf(e_io[(size_t)idx * HEADS + h] - m_[(b * N + d) * HEADS + h]);
    e_io[(size_t)idx * HEADS + h] = ex;
    unsafeAtomicAdd(&den_[(b * N + d) * HEADS + h], ex);
  }
}

// ---- pass 3: alpha = ex/den[dst]; rowsum[src] += alpha ----
__global__ void k_edge_alpha(const int* __restrict__ ei, const float* __restrict__ den_,
                             float* __restrict__ e_io, float* __restrict__ rs_) {
  int idx = blockIdx.x * blockDim.x + threadIdx.x;
  if (idx >= B * E) return;
  int eidx = idx & (E - 1), b = idx >> 15;
  int s = ei[eidx], d = ei[E + eidx];
#pragma unroll
  for (int h = 0; h < HEADS; h++) {
    float alpha = e_io[(size_t)idx * HEADS + h] / den_[(b * N + d) * HEADS + h];
    e_io[(size_t)idx * HEADS + h] = alpha;
    unsafeAtomicAdd(&rs_[(b * N + s) * HEADS + h], alpha);
  }
}

// ---- pass 4: out[dst] += alpha * x[src]; A[b,h,src,dst] += alpha/rowsum[src] ----
__global__ void k_edge_scatter(const int* __restrict__ ei, const float* __restrict__ e_io,
                               const float* __restrict__ rs_, const float* __restrict__ x_,
                               float* __restrict__ out, float* __restrict__ A) {
  int idx = blockIdx.x * blockDim.x + threadIdx.x;
  if (idx >= B * E) return;
  int eidx = idx & (E - 1), b = idx >> 15;
  int s = ei[eidx], d = ei[E + eidx];
  const float* xr = x_ + ((size_t)(b * N + s)) * (HEADS * OC);
  float* orow = out + ((size_t)(b * N + d)) * (HEADS * OC);
#pragma unroll
  for (int h = 0; h < HEADS; h++) {
    float alpha = e_io[(size_t)idx * HEADS + h];
    float rs = rs_[(b * N + s) * HEADS + h];
    float an = alpha / fmaxf(rs, 1e-9f);
    unsafeAtomicAdd(&A[(((size_t)b * HEADS + h) * N + s) * N + d], an);
#pragma unroll
    for (int oc = 0; oc < OC; oc++) {
      unsafeAtomicAdd(&orow[h * OC + oc], alpha * xr[h * OC + oc]);
    }
  }
}

}  // namespace

extern "C" void kernel_launch(void* const* d_in, const int* in_sizes, int n_in,
                              void* d_out, int out_size, void* d_ws, size_t ws_size,
                              hipStream_t stream) {
  const float* H      = (const float*)d_in[0];
  const int*   ei     = (const int*)  d_in[1];
  const float* fc_s_w = (const float*)d_in[2];
  const float* fc_s_b = (const float*)d_in[3];
  const float* fc_a_w = (const float*)d_in[4];
  const float* fc_a_b = (const float*)d_in[5];
  const float* fc_r_w = (const float*)d_in[6];
  const float* fc_r_b = (const float*)d_in[7];
  const float* fuse_q = (const float*)d_in[8];
  const float* fuse_k_w = (const float*)d_in[9];
  const float* fuse_v_w = (const float*)d_in[10];
  const float* proj_w = (const float*)d_in[11];
  const float* proj_b = (const float*)d_in[12];
  const float* post_w = (const float*)d_in[13];
  const float* post_b = (const float*)d_in[14];
  const float* ln_g   = (const float*)d_in[15];
  const float* ln_b   = (const float*)d_in[16];
  const float* gat_w  = (const float*)d_in[17];
  const float* att_src = (const float*)d_in[18];
  const float* att_dst = (const float*)d_in[19];
  const float* gat_b  = (const float*)d_in[20];

  float* out = (float*)d_out;                       // (B,N,32)
  float* A   = out + (size_t)B * N * DO;            // (B,4,N,N)

  float* ws   = (float*)d_ws;
  float* xbuf = ws;                                 // B*N*32
  float* asb  = xbuf + (size_t)B * N * (HEADS * OC);// B*N*4
  float* adb  = asb + (size_t)B * N * HEADS;        // B*N*4
  float* mbuf = adb + (size_t)B * N * HEADS;        // B*N*4
  float* denb = mbuf + (size_t)B * N * HEADS;       // B*N*4
  float* rsb  = denb + (size_t)B * N * HEADS;       // B*N*4
  float* ebuf = rsb + (size_t)B * N * HEADS;        // B*E*4

  hipMemsetAsync(A, 0, (size_t)B * HEADS * N * N * sizeof(float), stream);
  k_init<<<dim3((B * N * DO + 255) / 256), dim3(256), 0, stream>>>(out, gat_b, mbuf, denb, rsb);
  k_node<<<dim3((B * N) / 64), dim3(64), 0, stream>>>(
      H, fc_s_w, fc_s_b, fc_a_w, fc_a_b, fc_r_w, fc_r_b, fuse_q, fuse_k_w,
      fuse_v_w, proj_w, proj_b, post_w, post_b, ln_g, ln_b, gat_w, att_src,
      att_dst, xbuf, asb, adb);
  int nbe = B * E;
  k_edge_max<<<dim3(nbe / 256), dim3(256), 0, stream>>>(ei, asb, adb, ebuf, mbuf);
  k_edge_exp<<<dim3(nbe / 256), dim3(256), 0, stream>>>(ei, mbuf, ebuf, denb);
  k_edge_alpha<<<dim3(nbe / 256), dim3(256), 0, stream>>>(ei, denb, ebuf, rsb);
  k_edge_scatter<<<dim3(nbe / 256), dim3(256), 0, stream>>>(ei, ebuf, rsb, xbuf, out, A);
}

// Round 3
// 182.655 us; speedup vs baseline: 7.2725x; 7.2725x over previous
//
#include <hip/hip_runtime.h>
#include <math.h>

namespace {

constexpr int B = 16, N = 1024, E = 32768, HEADS = 4, OC = 8;
constexpr int D_IN = 33, A_DIM = 8, DM = 16, DO = 32;
constexpr int F = D_IN + A_DIM + 1;  // 42

typedef float f4 __attribute__((ext_vector_type(4)));

__device__ __forceinline__ float lrelu(float x) { return x >= 0.f ? x : 0.2f * x; }

// ---- per-node chain: fc_* -> fuse attn -> proj -> post -> LN -> gat_w -> a_s/a_d ----
__global__ __launch_bounds__(64) void k_node(
    const float* __restrict__ H,
    const float* __restrict__ fc_s_w, const float* __restrict__ fc_s_b,
    const float* __restrict__ fc_a_w, const float* __restrict__ fc_a_b,
    const float* __restrict__ fc_r_w, const float* __restrict__ fc_r_b,
    const float* __restrict__ fuse_q, const float* __restrict__ fuse_k_w,
    const float* __restrict__ fuse_v_w, const float* __restrict__ proj_w,
    const float* __restrict__ proj_b, const float* __restrict__ post_w,
    const float* __restrict__ post_b, const float* __restrict__ ln_g,
    const float* __restrict__ ln_b, const float* __restrict__ gat_w,
    const float* __restrict__ att_src, const float* __restrict__ att_dst,
    float* __restrict__ x_out, float* __restrict__ as_out, float* __restrict__ ad_out) {
  int node = blockIdx.x * blockDim.x + threadIdx.x;
  if (node >= B * N) return;

  const float* hin = H + (size_t)node * F;
  float hv[F];
#pragma unroll
  for (int i = 0; i < F; i++) hv[i] = hin[i];

  float tok[3][DM];
#pragma unroll
  for (int j = 0; j < DM; j++) {
    float acc = fc_s_b[j];
#pragma unroll
    for (int i = 0; i < D_IN; i++) acc = fmaf(hv[i], fc_s_w[j * D_IN + i], acc);
    tok[0][j] = acc;
    float acc2 = fc_a_b[j];
#pragma unroll
    for (int i = 0; i < A_DIM; i++) acc2 = fmaf(hv[D_IN + i], fc_a_w[j * A_DIM + i], acc2);
    tok[1][j] = acc2;
    tok[2][j] = fmaf(hv[F - 1], fc_r_w[j], fc_r_b[j]);
  }

  float Kf[3][DM], Vf[3][DM];
#pragma unroll
  for (int t = 0; t < 3; t++) {
#pragma unroll
    for (int j = 0; j < DM; j++) {
      float ak = 0.f, av = 0.f;
#pragma unroll
      for (int d = 0; d < DM; d++) {
        ak = fmaf(tok[t][d], fuse_k_w[j * DM + d], ak);
        av = fmaf(tok[t][d], fuse_v_w[j * DM + d], av);
      }
      Kf[t][j] = ak; Vf[t][j] = av;
    }
  }

  float wbar[3] = {0.f, 0.f, 0.f};
#pragma unroll
  for (int q = 0; q < 3; q++) {
    float att[3];
#pragma unroll
    for (int t = 0; t < 3; t++) {
      float acc = 0.f;
#pragma unroll
      for (int d = 0; d < DM; d++) acc = fmaf(fuse_q[q * DM + d], Kf[t][d], acc);
      att[t] = acc * 0.25f;
    }
    float mx = fmaxf(att[0], fmaxf(att[1], att[2]));
    float e0 = expf(att[0] - mx), e1 = expf(att[1] - mx), e2 = expf(att[2] - mx);
    float inv = 1.f / (e0 + e1 + e2);
    wbar[0] += e0 * inv; wbar[1] += e1 * inv; wbar[2] += e2 * inv;
  }

  float fused[DM];
#pragma unroll
  for (int d = 0; d < DM; d++) {
    float f = (wbar[0] * Vf[0][d] + wbar[1] * Vf[1][d] + wbar[2] * Vf[2][d]) * (1.f / 3.f);
    fused[d] = fmaxf(f, 0.f);
  }

  float z[DO];
#pragma unroll
  for (int o = 0; o < DO; o++) {
    float acc = proj_b[o];
#pragma unroll
    for (int d = 0; d < DM; d++) acc = fmaf(fused[d], proj_w[o * DM + d], acc);
    z[o] = acc;
  }

  float h2[DO]; float mu = 0.f;
#pragma unroll
  for (int o = 0; o < DO; o++) {
    float acc = post_b[o];
#pragma unroll
    for (int d = 0; d < DO; d++) acc = fmaf(z[d], post_w[o * DO + d], acc);
    acc = fmaxf(acc, 0.f);
    h2[o] = acc; mu += acc;
  }
  mu *= (1.f / DO);
  float var = 0.f;
#pragma unroll
  for (int o = 0; o < DO; o++) { float dd = h2[o] - mu; var = fmaf(dd, dd, var); }
  var *= (1.f / DO);
  float rstd = rsqrtf(var + 1e-5f);
  float Hn[DO];
#pragma unroll
  for (int o = 0; o < DO; o++) Hn[o] = fmaf((h2[o] - mu) * rstd, ln_g[o], ln_b[o]);

  float* xrow = x_out + (size_t)node * (HEADS * OC);
#pragma unroll
  for (int hh = 0; hh < HEADS; hh++) {
    float as = 0.f, ad = 0.f;
#pragma unroll
    for (int oc = 0; oc < OC; oc++) {
      int k = hh * OC + oc;
      float acc = 0.f;
#pragma unroll
      for (int d = 0; d < DO; d++) acc = fmaf(Hn[d], gat_w[k * DO + d], acc);
      xrow[k] = acc;
      as = fmaf(acc, att_src[k], as);
      ad = fmaf(acc, att_dst[k], ad);
    }
    as_out[node * HEADS + hh] = as;
    ad_out[node * HEADS + hh] = ad;
  }
}

// ---- CSR build: histogram ----
__global__ void k_hist(const int* __restrict__ ei, int* __restrict__ cnt_src,
                       int* __restrict__ cnt_dst) {
  int e = blockIdx.x * blockDim.x + threadIdx.x;
  if (e >= E) return;
  atomicAdd(&cnt_src[ei[e]], 1);
  atomicAdd(&cnt_dst[ei[E + e]], 1);
}

// ---- CSR build: exclusive scan (single block, N=1024 bins) ----
__global__ __launch_bounds__(1024) void k_scan(
    const int* __restrict__ cnt_src, const int* __restrict__ cnt_dst,
    int* __restrict__ off_src, int* __restrict__ off_dst,
    int* __restrict__ cur_src, int* __restrict__ cur_dst) {
  __shared__ int tmp[N];
  int t = threadIdx.x;

  tmp[t] = cnt_src[t]; __syncthreads();
  for (int off = 1; off < N; off <<= 1) {
    int add = (t >= off) ? tmp[t - off] : 0;
    __syncthreads();
    tmp[t] += add;
    __syncthreads();
  }
  off_src[t + 1] = tmp[t];
  if (t == 0) off_src[0] = 0;
  cur_src[t] = (t == 0) ? 0 : tmp[t - 1];
  __syncthreads();

  tmp[t] = cnt_dst[t]; __syncthreads();
  for (int off = 1; off < N; off <<= 1) {
    int add = (t >= off) ? tmp[t - off] : 0;
    __syncthreads();
    tmp[t] += add;
    __syncthreads();
  }
  off_dst[t + 1] = tmp[t];
  if (t == 0) off_dst[0] = 0;
  cur_dst[t] = (t == 0) ? 0 : tmp[t - 1];
}

// ---- CSR build: fill edge lists ----
__global__ void k_fill(const int* __restrict__ ei, int* __restrict__ cur_src,
                       int* __restrict__ cur_dst, int* __restrict__ elist_src,
                       int* __restrict__ elist_dst) {
  int e = blockIdx.x * blockDim.x + threadIdx.x;
  if (e >= E) return;
  int p1 = atomicAdd(&cur_src[ei[e]], 1);
  elist_src[p1] = e;
  int p2 = atomicAdd(&cur_dst[ei[E + e]], 1);
  elist_dst[p2] = e;
}

// ---- per-(b,dst) gather: softmax over incoming edges + alpha + out ----
__global__ __launch_bounds__(64) void k_dst(
    const int* __restrict__ ei, const int* __restrict__ off_dst,
    const int* __restrict__ elist_dst, const float* __restrict__ as_,
    const float* __restrict__ ad_, const float* __restrict__ x_,
    const float* __restrict__ gat_b, float* __restrict__ alpha_,
    float* __restrict__ out) {
  int bd = blockIdx.x;
  int b = bd >> 10, dn = bd & (N - 1);
  int lane = threadIdx.x;
  int beg = off_dst[dn];
  int deg = off_dst[dn + 1] - beg;

  const float* adp = ad_ + (size_t)(b * N + dn) * HEADS;
  float adv0 = adp[0], adv1 = adp[1], adv2 = adp[2], adv3 = adp[3];

  // pass 1: per-head max
  float mx0 = -INFINITY, mx1 = -INFINITY, mx2 = -INFINITY, mx3 = -INFINITY;
  for (int i = lane; i < deg; i += 64) {
    int e = elist_dst[beg + i];
    int s = ei[e];
    const float* ap = as_ + (size_t)(b * N + s) * HEADS;
    mx0 = fmaxf(mx0, lrelu(ap[0] + adv0));
    mx1 = fmaxf(mx1, lrelu(ap[1] + adv1));
    mx2 = fmaxf(mx2, lrelu(ap[2] + adv2));
    mx3 = fmaxf(mx3, lrelu(ap[3] + adv3));
  }
#pragma unroll
  for (int off = 1; off < 64; off <<= 1) {
    mx0 = fmaxf(mx0, __shfl_xor(mx0, off));
    mx1 = fmaxf(mx1, __shfl_xor(mx1, off));
    mx2 = fmaxf(mx2, __shfl_xor(mx2, off));
    mx3 = fmaxf(mx3, __shfl_xor(mx3, off));
  }

  // pass 2: per-head denominator
  float sm0 = 0.f, sm1 = 0.f, sm2 = 0.f, sm3 = 0.f;
  for (int i = lane; i < deg; i += 64) {
    int e = elist_dst[beg + i];
    int s = ei[e];
    const float* ap = as_ + (size_t)(b * N + s) * HEADS;
    sm0 += __expf(lrelu(ap[0] + adv0) - mx0);
    sm1 += __expf(lrelu(ap[1] + adv1) - mx1);
    sm2 += __expf(lrelu(ap[2] + adv2) - mx2);
    sm3 += __expf(lrelu(ap[3] + adv3) - mx3);
  }
#pragma unroll
  for (int off = 1; off < 64; off <<= 1) {
    sm0 += __shfl_xor(sm0, off);
    sm1 += __shfl_xor(sm1, off);
    sm2 += __shfl_xor(sm2, off);
    sm3 += __shfl_xor(sm3, off);
  }
  float inv0 = 1.f / sm0, inv1 = 1.f / sm1, inv2 = 1.f / sm2, inv3 = 1.f / sm3;

  // pass 3: write normalized alpha per edge (indexed by original edge id)
  for (int i = lane; i < deg; i += 64) {
    int e = elist_dst[beg + i];
    int s = ei[e];
    const float* ap = as_ + (size_t)(b * N + s) * HEADS;
    f4 al;
    al.x = __expf(lrelu(ap[0] + adv0) - mx0) * inv0;
    al.y = __expf(lrelu(ap[1] + adv1) - mx1) * inv1;
    al.z = __expf(lrelu(ap[2] + adv2) - mx2) * inv2;
    al.w = __expf(lrelu(ap[3] + adv3) - mx3) * inv3;
    *(f4*)(alpha_ + ((size_t)b * E + e) * HEADS) = al;
  }

  // phase B: out[b,dn,c] = gat_b[c] + sum_e alpha[e,h(c)] * x[src,c]
  int c = lane & 31;
  int h3 = c >> 3;
  float mh  = h3 == 0 ? mx0  : h3 == 1 ? mx1  : h3 == 2 ? mx2  : mx3;
  float ih  = h3 == 0 ? inv0 : h3 == 1 ? inv1 : h3 == 2 ? inv2 : inv3;
  float adh = h3 == 0 ? adv0 : h3 == 1 ? adv1 : h3 == 2 ? adv2 : adv3;
  float acc = 0.f;
  for (int i = (lane >> 5); i < deg; i += 2) {
    int e = elist_dst[beg + i];
    int s = ei[e];
    float av = as_[(size_t)(b * N + s) * HEADS + h3];
    float al = __expf(lrelu(av + adh) - mh) * ih;
    acc = fmaf(al, x_[(size_t)(b * N + s) * (HEADS * OC) + c], acc);
  }
  acc += __shfl_xor(acc, 32);
  if (lane < 32) out[(size_t)bd * (HEADS * OC) + c] = acc + gat_b[c];
}

// ---- per-(b,src) dense A row: LDS accumulate + normalize + stream write ----
__global__ __launch_bounds__(256) void k_A(
    const int* __restrict__ ei, const int* __restrict__ off_src,
    const int* __restrict__ elist_src, const float* __restrict__ alpha_,
    float* __restrict__ A) {
  __shared__ float row[HEADS][N];
  __shared__ float rsum[HEADS];
  int bs = blockIdx.x;
  int b = bs >> 10, s = bs & (N - 1);
  int t = threadIdx.x;

  for (int i = t; i < HEADS * N; i += 256) ((float*)row)[i] = 0.f;
  if (t < HEADS) rsum[t] = 0.f;
  __syncthreads();

  int beg = off_src[s], end = off_src[s + 1];
  for (int i = beg + t; i < end; i += 256) {
    int e = elist_src[i];
    int d = ei[E + e];
    f4 al = *(const f4*)(alpha_ + ((size_t)b * E + e) * HEADS);
    atomicAdd(&row[0][d], al.x);
    atomicAdd(&row[1][d], al.y);
    atomicAdd(&row[2][d], al.z);
    atomicAdd(&row[3][d], al.w);
    atomicAdd(&rsum[0], al.x);
    atomicAdd(&rsum[1], al.y);
    atomicAdd(&rsum[2], al.z);
    atomicAdd(&rsum[3], al.w);
  }
  __syncthreads();

#pragma unroll
  for (int h = 0; h < HEADS; h++) {
    float ivh = 1.f / fmaxf(rsum[h], 1e-9f);
    f4 v = *(f4*)&row[h][t * 4];
    v.x *= ivh; v.y *= ivh; v.z *= ivh; v.w *= ivh;
    f4* dst = (f4*)(A + (((size_t)b * HEADS + h) * N + s) * N) + t;
    __builtin_nontemporal_store(v, dst);
  }
}

}  // namespace

extern "C" void kernel_launch(void* const* d_in, const int* in_sizes, int n_in,
                              void* d_out, int out_size, void* d_ws, size_t ws_size,
                              hipStream_t stream) {
  const float* H      = (const float*)d_in[0];
  const int*   ei     = (const int*)  d_in[1];
  const float* fc_s_w = (const float*)d_in[2];
  const float* fc_s_b = (const float*)d_in[3];
  const float* fc_a_w = (const float*)d_in[4];
  const float* fc_a_b = (const float*)d_in[5];
  const float* fc_r_w = (const float*)d_in[6];
  const float* fc_r_b = (const float*)d_in[7];
  const float* fuse_q = (const float*)d_in[8];
  const float* fuse_k_w = (const float*)d_in[9];
  const float* fuse_v_w = (const float*)d_in[10];
  const float* proj_w = (const float*)d_in[11];
  const float* proj_b = (const float*)d_in[12];
  const float* post_w = (const float*)d_in[13];
  const float* post_b = (const float*)d_in[14];
  const float* ln_g   = (const float*)d_in[15];
  const float* ln_b   = (const float*)d_in[16];
  const float* gat_w  = (const float*)d_in[17];
  const float* att_src = (const float*)d_in[18];
  const float* att_dst = (const float*)d_in[19];
  const float* gat_b  = (const float*)d_in[20];

  float* out = (float*)d_out;                        // (B,N,32)
  float* A   = out + (size_t)B * N * DO;             // (B,4,N,N)

  // ws layout
  float* ws    = (float*)d_ws;
  float* xbuf  = ws;                                 // B*N*32
  float* asb   = xbuf + (size_t)B * N * (HEADS * OC);
  float* adb   = asb + (size_t)B * N * HEADS;
  float* alpha = adb + (size_t)B * N * HEADS;        // B*E*4
  int* ibase     = (int*)(alpha + (size_t)B * E * HEADS);
  int* cnt_src   = ibase;            // 1024
  int* cnt_dst   = cnt_src + N;      // 1024
  int* off_src   = cnt_dst + N;      // 1025
  int* off_dst   = off_src + (N + 1);
  int* cur_src   = off_dst + (N + 1);
  int* cur_dst   = cur_src + N;
  int* elist_src = cur_dst + N;      // E
  int* elist_dst = elist_src + E;    // E

  (void)hipMemsetAsync(cnt_src, 0, 2 * N * sizeof(int), stream);
  k_hist<<<dim3(E / 256), dim3(256), 0, stream>>>(ei, cnt_src, cnt_dst);
  k_scan<<<dim3(1), dim3(N), 0, stream>>>(cnt_src, cnt_dst, off_src, off_dst, cur_src, cur_dst);
  k_fill<<<dim3(E / 256), dim3(256), 0, stream>>>(ei, cur_src, cur_dst, elist_src, elist_dst);

  k_node<<<dim3((B * N) / 64), dim3(64), 0, stream>>>(
      H, fc_s_w, fc_s_b, fc_a_w, fc_a_b, fc_r_w, fc_r_b, fuse_q, fuse_k_w,
      fuse_v_w, proj_w, proj_b, post_w, post_b, ln_g, ln_b, gat_w, att_src,
      att_dst, xbuf, asb, adb);

  k_dst<<<dim3(B * N), dim3(64), 0, stream>>>(ei, off_dst, elist_dst, asb, adb,
                                              xbuf, gat_b, alpha, out);
  k_A<<<dim3(B * N), dim3(256), 0, stream>>>(ei, off_src, elist_src, alpha, A);
}

// Round 4
// 149.755 us; speedup vs baseline: 8.8702x; 1.2197x over previous
//
#include <hip/hip_runtime.h>
#include <math.h>

namespace {

constexpr int B = 16, N = 1024, E = 32768, HEADS = 4, OC = 8;
constexpr int D_IN = 33, A_DIM = 8, DM = 16, DO = 32;
constexpr int F = D_IN + A_DIM + 1;  // 42
constexpr int CAP = 256;             // LDS-cached incoming-edge capacity per dst

typedef float f4 __attribute__((ext_vector_type(4)));

__device__ __forceinline__ float lrelu(float x) { return x >= 0.f ? x : 0.2f * x; }

// ---- per-node chain: fc_* -> fuse attn -> proj -> post -> LN -> gat_w -> a_s/a_d ----
__global__ __launch_bounds__(64) void k_node(
    const float* __restrict__ H,
    const float* __restrict__ fc_s_w, const float* __restrict__ fc_s_b,
    const float* __restrict__ fc_a_w, const float* __restrict__ fc_a_b,
    const float* __restrict__ fc_r_w, const float* __restrict__ fc_r_b,
    const float* __restrict__ fuse_q, const float* __restrict__ fuse_k_w,
    const float* __restrict__ fuse_v_w, const float* __restrict__ proj_w,
    const float* __restrict__ proj_b, const float* __restrict__ post_w,
    const float* __restrict__ post_b, const float* __restrict__ ln_g,
    const float* __restrict__ ln_b, const float* __restrict__ gat_w,
    const float* __restrict__ att_src, const float* __restrict__ att_dst,
    float* __restrict__ x_out, float* __restrict__ as_out, float* __restrict__ ad_out) {
  int node = blockIdx.x * blockDim.x + threadIdx.x;
  if (node >= B * N) return;

  const float* hin = H + (size_t)node * F;
  float hv[F];
#pragma unroll
  for (int i = 0; i < F; i++) hv[i] = hin[i];

  float tok[3][DM];
#pragma unroll
  for (int j = 0; j < DM; j++) {
    float acc = fc_s_b[j];
#pragma unroll
    for (int i = 0; i < D_IN; i++) acc = fmaf(hv[i], fc_s_w[j * D_IN + i], acc);
    tok[0][j] = acc;
    float acc2 = fc_a_b[j];
#pragma unroll
    for (int i = 0; i < A_DIM; i++) acc2 = fmaf(hv[D_IN + i], fc_a_w[j * A_DIM + i], acc2);
    tok[1][j] = acc2;
    tok[2][j] = fmaf(hv[F - 1], fc_r_w[j], fc_r_b[j]);
  }

  float Kf[3][DM], Vf[3][DM];
#pragma unroll
  for (int t = 0; t < 3; t++) {
#pragma unroll
    for (int j = 0; j < DM; j++) {
      float ak = 0.f, av = 0.f;
#pragma unroll
      for (int d = 0; d < DM; d++) {
        ak = fmaf(tok[t][d], fuse_k_w[j * DM + d], ak);
        av = fmaf(tok[t][d], fuse_v_w[j * DM + d], av);
      }
      Kf[t][j] = ak; Vf[t][j] = av;
    }
  }

  float wbar[3] = {0.f, 0.f, 0.f};
#pragma unroll
  for (int q = 0; q < 3; q++) {
    float att[3];
#pragma unroll
    for (int t = 0; t < 3; t++) {
      float acc = 0.f;
#pragma unroll
      for (int d = 0; d < DM; d++) acc = fmaf(fuse_q[q * DM + d], Kf[t][d], acc);
      att[t] = acc * 0.25f;
    }
    float mx = fmaxf(att[0], fmaxf(att[1], att[2]));
    float e0 = expf(att[0] - mx), e1 = expf(att[1] - mx), e2 = expf(att[2] - mx);
    float inv = 1.f / (e0 + e1 + e2);
    wbar[0] += e0 * inv; wbar[1] += e1 * inv; wbar[2] += e2 * inv;
  }

  float fused[DM];
#pragma unroll
  for (int d = 0; d < DM; d++) {
    float f = (wbar[0] * Vf[0][d] + wbar[1] * Vf[1][d] + wbar[2] * Vf[2][d]) * (1.f / 3.f);
    fused[d] = fmaxf(f, 0.f);
  }

  float z[DO];
#pragma unroll
  for (int o = 0; o < DO; o++) {
    float acc = proj_b[o];
#pragma unroll
    for (int d = 0; d < DM; d++) acc = fmaf(fused[d], proj_w[o * DM + d], acc);
    z[o] = acc;
  }

  float h2[DO]; float mu = 0.f;
#pragma unroll
  for (int o = 0; o < DO; o++) {
    float acc = post_b[o];
#pragma unroll
    for (int d = 0; d < DO; d++) acc = fmaf(z[d], post_w[o * DO + d], acc);
    acc = fmaxf(acc, 0.f);
    h2[o] = acc; mu += acc;
  }
  mu *= (1.f / DO);
  float var = 0.f;
#pragma unroll
  for (int o = 0; o < DO; o++) { float dd = h2[o] - mu; var = fmaf(dd, dd, var); }
  var *= (1.f / DO);
  float rstd = rsqrtf(var + 1e-5f);
  float Hn[DO];
#pragma unroll
  for (int o = 0; o < DO; o++) Hn[o] = fmaf((h2[o] - mu) * rstd, ln_g[o], ln_b[o]);

  float* xrow = x_out + (size_t)node * (HEADS * OC);
#pragma unroll
  for (int hh = 0; hh < HEADS; hh++) {
    float as = 0.f, ad = 0.f;
#pragma unroll
    for (int oc = 0; oc < OC; oc++) {
      int k = hh * OC + oc;
      float acc = 0.f;
#pragma unroll
      for (int d = 0; d < DO; d++) acc = fmaf(Hn[d], gat_w[k * DO + d], acc);
      xrow[k] = acc;
      as = fmaf(acc, att_src[k], as);
      ad = fmaf(acc, att_dst[k], ad);
    }
    as_out[node * HEADS + hh] = as;
    ad_out[node * HEADS + hh] = ad;
  }
}

// ---- CSR build: histogram ----
__global__ void k_hist(const int* __restrict__ ei, int* __restrict__ cnt_src,
                       int* __restrict__ cnt_dst) {
  int e = blockIdx.x * blockDim.x + threadIdx.x;
  if (e >= E) return;
  atomicAdd(&cnt_src[ei[e]], 1);
  atomicAdd(&cnt_dst[ei[E + e]], 1);
}

// ---- CSR build: shfl-based exclusive scan, both arrays, 1024 bins each ----
__global__ __launch_bounds__(1024) void k_scan(
    const int* __restrict__ cnt_src, const int* __restrict__ cnt_dst,
    int* __restrict__ off_src, int* __restrict__ off_dst,
    int* __restrict__ cur_src, int* __restrict__ cur_dst) {
  __shared__ int ws[16];
  int t = threadIdx.x, lane = t & 63, w = t >> 6;

  {
    int v = cnt_src[t], sc = v;
#pragma unroll
    for (int o = 1; o < 64; o <<= 1) { int u = __shfl_up(sc, o); if (lane >= o) sc += u; }
    if (lane == 63) ws[w] = sc;
    __syncthreads();
    if (w == 0) {
      int x = lane < 16 ? ws[lane] : 0;
#pragma unroll
      for (int o = 1; o < 16; o <<= 1) { int u = __shfl_up(x, o); if (lane >= o) x += u; }
      if (lane < 16) ws[lane] = x;
    }
    __syncthreads();
    int inc = sc + (w ? ws[w - 1] : 0);
    off_src[t + 1] = inc;
    if (t == 0) off_src[0] = 0;
    cur_src[t] = inc - v;
    __syncthreads();
  }
  {
    int v = cnt_dst[t], sc = v;
#pragma unroll
    for (int o = 1; o < 64; o <<= 1) { int u = __shfl_up(sc, o); if (lane >= o) sc += u; }
    if (lane == 63) ws[w] = sc;
    __syncthreads();
    if (w == 0) {
      int x = lane < 16 ? ws[lane] : 0;
#pragma unroll
      for (int o = 1; o < 16; o <<= 1) { int u = __shfl_up(x, o); if (lane >= o) x += u; }
      if (lane < 16) ws[lane] = x;
    }
    __syncthreads();
    int inc = sc + (w ? ws[w - 1] : 0);
    off_dst[t + 1] = inc;
    if (t == 0) off_dst[0] = 0;
    cur_dst[t] = inc - v;
  }
}

// ---- CSR build: fill edge lists ----
__global__ void k_fill(const int* __restrict__ ei, int* __restrict__ cur_src,
                       int* __restrict__ cur_dst, int* __restrict__ elist_src,
                       int* __restrict__ elist_dst) {
  int e = blockIdx.x * blockDim.x + threadIdx.x;
  if (e >= E) return;
  int p1 = atomicAdd(&cur_src[ei[e]], 1);
  elist_src[p1] = e;
  int p2 = atomicAdd(&cur_dst[ei[E + e]], 1);
  elist_dst[p2] = e;
}

// ---- per-(b,dst): one gather pass -> den/inv ; then out accumulation ----
// No max-subtraction: scores bounded (|e| ~ O(10)), exp safely in fp32 range.
__global__ __launch_bounds__(64) void k_dst(
    const int* __restrict__ ei, const int* __restrict__ off_dst,
    const int* __restrict__ elist_dst, const float* __restrict__ as_,
    const float* __restrict__ ad_, const float* __restrict__ x_,
    const float* __restrict__ gat_b, float* __restrict__ invb,
    float* __restrict__ out) {
  __shared__ float s_al[CAP][HEADS];  // unnormalized exp scores
  __shared__ int s_src[CAP];
  int bd = blockIdx.x;
  int b = bd >> 10, dn = bd & (N - 1);
  int lane = threadIdx.x;
  int beg = off_dst[dn];
  int deg = off_dst[dn + 1] - beg;

  f4 adv = *(const f4*)(ad_ + (size_t)(b * N + dn) * HEADS);

  float sm0 = 0.f, sm1 = 0.f, sm2 = 0.f, sm3 = 0.f;
  for (int i = lane; i < deg; i += 64) {
    int e = elist_dst[beg + i];
    int s = ei[e];
    f4 ap = *(const f4*)(as_ + (size_t)(b * N + s) * HEADS);
    float e0 = __expf(lrelu(ap.x + adv.x));
    float e1 = __expf(lrelu(ap.y + adv.y));
    float e2 = __expf(lrelu(ap.z + adv.z));
    float e3 = __expf(lrelu(ap.w + adv.w));
    if (i < CAP) {
      s_src[i] = s;
      s_al[i][0] = e0; s_al[i][1] = e1; s_al[i][2] = e2; s_al[i][3] = e3;
    }
    sm0 += e0; sm1 += e1; sm2 += e2; sm3 += e3;
  }
#pragma unroll
  for (int off = 1; off < 64; off <<= 1) {
    sm0 += __shfl_xor(sm0, off);
    sm1 += __shfl_xor(sm1, off);
    sm2 += __shfl_xor(sm2, off);
    sm3 += __shfl_xor(sm3, off);
  }
  f4 inv;
  inv.x = 1.f / sm0; inv.y = 1.f / sm1; inv.z = 1.f / sm2; inv.w = 1.f / sm3;
  if (lane == 0) *(f4*)(invb + (size_t)(b * N + dn) * HEADS) = inv;

  __syncthreads();

  // out[b,dn,c] = gat_b[c] + inv[h] * sum_e ex[e,h] * x[src,c]
  int c = lane & 31;
  int h3 = c >> 3;
  float ih  = h3 == 0 ? inv.x : h3 == 1 ? inv.y : h3 == 2 ? inv.z : inv.w;
  float adh = h3 == 0 ? adv.x : h3 == 1 ? adv.y : h3 == 2 ? adv.z : adv.w;
  float acc = 0.f;
  for (int i = (lane >> 5); i < deg; i += 2) {
    float exv; int s;
    if (i < CAP) {
      exv = s_al[i][h3];
      s = s_src[i];
    } else {
      int e = elist_dst[beg + i];
      s = ei[e];
      exv = __expf(lrelu(as_[(size_t)(b * N + s) * HEADS + h3] + adh));
    }
    acc = fmaf(exv, x_[(size_t)(b * N + s) * (HEADS * OC) + c], acc);
  }
  acc += __shfl_xor(acc, 32);
  if (lane < 32) out[(size_t)bd * (HEADS * OC) + c] = acc * ih + gat_b[c];
}

// ---- per-(b,src) dense A row: recompute alpha, LDS accumulate, normalize, stream ----
__global__ __launch_bounds__(256) void k_A(
    const int* __restrict__ ei, const int* __restrict__ off_src,
    const int* __restrict__ elist_src, const float* __restrict__ as_,
    const float* __restrict__ ad_, const float* __restrict__ invb,
    float* __restrict__ A) {
  __shared__ float row[HEADS][N];
  __shared__ float rsum[HEADS];
  int bs = blockIdx.x;
  int b = bs >> 10, s = bs & (N - 1);
  int t = threadIdx.x;

  f4* rowv = (f4*)row;
  for (int i = t; i < HEADS * N / 4; i += 256) rowv[i] = (f4){0.f, 0.f, 0.f, 0.f};
  if (t < HEADS) rsum[t] = 0.f;
  __syncthreads();

  f4 asv = *(const f4*)(as_ + (size_t)(b * N + s) * HEADS);  // block-uniform
  int beg = off_src[s], end = off_src[s + 1];
  float r0 = 0.f, r1 = 0.f, r2 = 0.f, r3 = 0.f;
  for (int i = beg + t; i < end; i += 256) {
    int e = elist_src[i];
    int d = ei[E + e];
    f4 adv = *(const f4*)(ad_ + (size_t)(b * N + d) * HEADS);
    f4 iv  = *(const f4*)(invb + (size_t)(b * N + d) * HEADS);
    float a0 = __expf(lrelu(asv.x + adv.x)) * iv.x;
    float a1 = __expf(lrelu(asv.y + adv.y)) * iv.y;
    float a2 = __expf(lrelu(asv.z + adv.z)) * iv.z;
    float a3 = __expf(lrelu(asv.w + adv.w)) * iv.w;
    atomicAdd(&row[0][d], a0);
    atomicAdd(&row[1][d], a1);
    atomicAdd(&row[2][d], a2);
    atomicAdd(&row[3][d], a3);
    r0 += a0; r1 += a1; r2 += a2; r3 += a3;
  }
#pragma unroll
  for (int off = 1; off < 64; off <<= 1) {
    r0 += __shfl_xor(r0, off);
    r1 += __shfl_xor(r1, off);
    r2 += __shfl_xor(r2, off);
    r3 += __shfl_xor(r3, off);
  }
  if ((t & 63) == 0) {
    atomicAdd(&rsum[0], r0);
    atomicAdd(&rsum[1], r1);
    atomicAdd(&rsum[2], r2);
    atomicAdd(&rsum[3], r3);
  }
  __syncthreads();

#pragma unroll
  for (int h = 0; h < HEADS; h++) {
    float ivh = 1.f / fmaxf(rsum[h], 1e-9f);
    f4 v = *(f4*)&row[h][t * 4];
    v.x *= ivh; v.y *= ivh; v.z *= ivh; v.w *= ivh;
    f4* dst = (f4*)(A + (((size_t)b * HEADS + h) * N + s) * N) + t;
    __builtin_nontemporal_store(v, dst);
  }
}

}  // namespace

extern "C" void kernel_launch(void* const* d_in, const int* in_sizes, int n_in,
                              void* d_out, int out_size, void* d_ws, size_t ws_size,
                              hipStream_t stream) {
  const float* H      = (const float*)d_in[0];
  const int*   ei     = (const int*)  d_in[1];
  const float* fc_s_w = (const float*)d_in[2];
  const float* fc_s_b = (const float*)d_in[3];
  const float* fc_a_w = (const float*)d_in[4];
  const float* fc_a_b = (const float*)d_in[5];
  const float* fc_r_w = (const float*)d_in[6];
  const float* fc_r_b = (const float*)d_in[7];
  const float* fuse_q = (const float*)d_in[8];
  const float* fuse_k_w = (const float*)d_in[9];
  const float* fuse_v_w = (const float*)d_in[10];
  const float* proj_w = (const float*)d_in[11];
  const float* proj_b = (const float*)d_in[12];
  const float* post_w = (const float*)d_in[13];
  const float* post_b = (const float*)d_in[14];
  const float* ln_g   = (const float*)d_in[15];
  const float* ln_b   = (const float*)d_in[16];
  const float* gat_w  = (const float*)d_in[17];
  const float* att_src = (const float*)d_in[18];
  const float* att_dst = (const float*)d_in[19];
  const float* gat_b  = (const float*)d_in[20];

  float* out = (float*)d_out;                        // (B,N,32)
  float* A   = out + (size_t)B * N * DO;             // (B,4,N,N)

  // ws layout
  float* ws   = (float*)d_ws;
  float* xbuf = ws;                                  // B*N*32
  float* asb  = xbuf + (size_t)B * N * (HEADS * OC); // B*N*4
  float* adb  = asb + (size_t)B * N * HEADS;         // B*N*4
  float* invb = adb + (size_t)B * N * HEADS;         // B*N*4
  int* ibase     = (int*)(invb + (size_t)B * N * HEADS);
  int* cnt_src   = ibase;            // 1024
  int* cnt_dst   = cnt_src + N;      // 1024
  int* off_src   = cnt_dst + N;      // 1025
  int* off_dst   = off_src + (N + 1);
  int* cur_src   = off_dst + (N + 1);
  int* cur_dst   = cur_src + N;
  int* elist_src = cur_dst + N;      // E
  int* elist_dst = elist_src + E;    // E

  (void)hipMemsetAsync(cnt_src, 0, 2 * N * sizeof(int), stream);
  k_hist<<<dim3(E / 256), dim3(256), 0, stream>>>(ei, cnt_src, cnt_dst);
  k_scan<<<dim3(1), dim3(N), 0, stream>>>(cnt_src, cnt_dst, off_src, off_dst, cur_src, cur_dst);
  k_fill<<<dim3(E / 256), dim3(256), 0, stream>>>(ei, cur_src, cur_dst, elist_src, elist_dst);

  k_node<<<dim3((B * N) / 64), dim3(64), 0, stream>>>(
      H, fc_s_w, fc_s_b, fc_a_w, fc_a_b, fc_r_w, fc_r_b, fuse_q, fuse_k_w,
      fuse_v_w, proj_w, proj_b, post_w, post_b, ln_g, ln_b, gat_w, att_src,
      att_dst, xbuf, asb, adb);

  k_dst<<<dim3(B * N), dim3(64), 0, stream>>>(ei, off_dst, elist_dst, asb, adb,
                                              xbuf, gat_b, invb, out);
  k_A<<<dim3(B * N), dim3(256), 0, stream>>>(ei, off_src, elist_src, asb, adb,
                                             invb, A);
}